// Round 1
// baseline (356.512 us; speedup 1.0000x reference)
//
#include <hip/hip_runtime.h>
#include <math.h>

#define BB   8
#define CIN  32
#define COUT 32
#define KK   81
#define PP   262144
#define PARTS 8
#define ROWS (BB * CIN)          // 256
#define CHUNK (PP / PARTS)       // 32768 floats per block
#define VEC_PER_THREAD (CHUNK / 4 / 256)  // 32 float4 per thread

// Kernel 1: row-wise sum over P. One block handles 1/8 of a row.
__global__ __launch_bounds__(256) void sph_reduce_rows(
    const float* __restrict__ in, float* __restrict__ partials) {
    const int blk  = blockIdx.x;      // 0..2047
    const int row  = blk >> 3;        // 0..255  (b*CIN + i)
    const int part = blk & 7;
    const int tid  = threadIdx.x;

    const float4* base =
        (const float4*)(in + (size_t)row * PP + (size_t)part * CHUNK);

    float acc = 0.0f;
#pragma unroll
    for (int j = 0; j < VEC_PER_THREAD; ++j) {
        float4 v = base[tid + j * 256];
        acc += (v.x + v.y) + (v.z + v.w);
    }
    // 64-lane wave reduce
#pragma unroll
    for (int off = 32; off > 0; off >>= 1)
        acc += __shfl_down(acc, off, 64);

    __shared__ float wsum[4];
    const int lane = tid & 63, wv = tid >> 6;
    if (lane == 0) wsum[wv] = acc;
    __syncthreads();
    if (tid == 0)
        partials[blk] = (wsum[0] + wsum[1]) + (wsum[2] + wsum[3]);
}

// Kernel 2: fold partials -> s[256] in LDS, then out[b,o,k] = Y[k]*dot(coeff[o,:,k], s[b,:])
__global__ __launch_bounds__(256) void sph_mix(
    const float* __restrict__ partials, const float* __restrict__ coeff,
    float* __restrict__ out) {
    __shared__ float s[ROWS];
    const int tid = threadIdx.x;

    // s[tid] = sum of 8 partials of row tid (two float4 loads)
    const float4* p4 = (const float4*)partials;
    float4 a = p4[tid * 2 + 0];
    float4 b4 = p4[tid * 2 + 1];
    s[tid] = ((a.x + a.y) + (a.z + a.w)) + ((b4.x + b4.y) + (b4.z + b4.w));
    __syncthreads();

    const int idx = blockIdx.x * 256 + tid;   // 81*256 == 20736 == B*COUT*K exactly
    const int k = idx % KK;
    const int o = (idx / KK) % COUT;
    const int b = idx / (KK * COUT);

    // l = floor(sqrt(k)), robust to fp rounding
    int l = (int)sqrtf((float)k);
    while (l * l > k) --l;
    while ((l + 1) * (l + 1) <= k) ++l;

    float y = 0.0f;
    if (k == l * l + l)  // m == 0
        y = sqrtf((float)(2 * l + 1) / (4.0f * (float)M_PI));

    const float* c  = coeff + o * (CIN * KK) + k;
    const float* sb = s + b * CIN;
    float acc = 0.0f;
#pragma unroll
    for (int i = 0; i < CIN; ++i)
        acc += c[i * KK] * sb[i];

    out[idx] = y * acc;
}

extern "C" void kernel_launch(void* const* d_in, const int* in_sizes, int n_in,
                              void* d_out, int out_size, void* d_ws, size_t ws_size,
                              hipStream_t stream) {
    const float* input = (const float*)d_in[0];   // [B, CIN, P]
    const float* coeff = (const float*)d_in[1];   // [COUT, CIN, K]
    float* out = (float*)d_out;                   // [B, COUT, K]
    float* partials = (float*)d_ws;               // 2048 floats

    sph_reduce_rows<<<ROWS * PARTS, 256, 0, stream>>>(input, partials);
    sph_mix<<<(BB * COUT * KK) / 256, 256, 0, stream>>>(partials, coeff, out);
}

// Round 3
// 330.781 us; speedup vs baseline: 1.0778x; 1.0778x over previous
//
#include <hip/hip_runtime.h>
#include <math.h>

#define BB   8
#define CIN  32
#define COUT 32
#define KK   81
#define PP   262144
#define PARTS 8
#define ROWS (BB * CIN)                   // 256
#define CHUNK (PP / PARTS)                // 32768 floats per block
#define VEC_PER_THREAD (CHUNK / 4 / 256)  // 32 float4 per thread

typedef float fvec4 __attribute__((ext_vector_type(4)));

// Kernel 1: row-wise sum over P. One block handles 1/8 of a row.
// 2048 blocks = 8/CU x 256 CU, 4 waves each -> full 32 waves/CU.
__global__ __launch_bounds__(256) void sph_reduce_rows(
    const float* __restrict__ in, float* __restrict__ partials) {
    const int blk  = blockIdx.x;      // 0..2047
    const int row  = blk >> 3;        // 0..255  (b*CIN + i)
    const int part = blk & 7;
    const int tid  = threadIdx.x;

    const fvec4* base =
        (const fvec4*)(in + (size_t)row * PP + (size_t)part * CHUNK);

    // 4 independent accumulators; non-temporal streaming loads (no reuse).
    float a0 = 0.0f, a1 = 0.0f, a2 = 0.0f, a3 = 0.0f;
#pragma unroll
    for (int j = 0; j < VEC_PER_THREAD; j += 4) {
        fvec4 v0 = __builtin_nontemporal_load(&base[tid + (j + 0) * 256]);
        fvec4 v1 = __builtin_nontemporal_load(&base[tid + (j + 1) * 256]);
        fvec4 v2 = __builtin_nontemporal_load(&base[tid + (j + 2) * 256]);
        fvec4 v3 = __builtin_nontemporal_load(&base[tid + (j + 3) * 256]);
        a0 += (v0.x + v0.y) + (v0.z + v0.w);
        a1 += (v1.x + v1.y) + (v1.z + v1.w);
        a2 += (v2.x + v2.y) + (v2.z + v2.w);
        a3 += (v3.x + v3.y) + (v3.z + v3.w);
    }
    float acc = (a0 + a1) + (a2 + a3);

    // 64-lane wave reduce
#pragma unroll
    for (int off = 32; off > 0; off >>= 1)
        acc += __shfl_down(acc, off, 64);

    __shared__ float wsum[4];
    const int lane = tid & 63, wv = tid >> 6;
    if (lane == 0) wsum[wv] = acc;
    __syncthreads();
    if (tid == 0)
        partials[blk] = (wsum[0] + wsum[1]) + (wsum[2] + wsum[3]);
}

// Kernel 2: fold partials -> s[256] in LDS, then
// out[b,o,k] = Y[k] * dot(coeff[o,:,k], s[b,:])
__global__ __launch_bounds__(256) void sph_mix(
    const float* __restrict__ partials, const float* __restrict__ coeff,
    float* __restrict__ out) {
    __shared__ float s[ROWS];
    const int tid = threadIdx.x;

    const float4* p4 = (const float4*)partials;
    float4 a = p4[tid * 2 + 0];
    float4 b4 = p4[tid * 2 + 1];
    s[tid] = ((a.x + a.y) + (a.z + a.w)) + ((b4.x + b4.y) + (b4.z + b4.w));
    __syncthreads();

    const int idx = blockIdx.x * 256 + tid;   // 81*256 == 20736 == B*COUT*K exactly
    const int k = idx % KK;
    const int o = (idx / KK) % COUT;
    const int b = idx / (KK * COUT);

    // l = floor(sqrt(k)), robust to fp rounding
    int l = (int)sqrtf((float)k);
    while (l * l > k) --l;
    while ((l + 1) * (l + 1) <= k) ++l;

    float y = 0.0f;
    if (k == l * l + l)  // m == 0
        y = sqrtf((float)(2 * l + 1) / (4.0f * (float)M_PI));

    const float* c  = coeff + o * (CIN * KK) + k;
    const float* sb = s + b * CIN;
    float acc = 0.0f;
#pragma unroll
    for (int i = 0; i < CIN; ++i)
        acc += c[i * KK] * sb[i];

    out[idx] = y * acc;
}

extern "C" void kernel_launch(void* const* d_in, const int* in_sizes, int n_in,
                              void* d_out, int out_size, void* d_ws, size_t ws_size,
                              hipStream_t stream) {
    const float* input = (const float*)d_in[0];   // [B, CIN, P]
    const float* coeff = (const float*)d_in[1];   // [COUT, CIN, K]
    float* out = (float*)d_out;                   // [B, COUT, K]
    float* partials = (float*)d_ws;               // 2048 floats

    sph_reduce_rows<<<ROWS * PARTS, 256, 0, stream>>>(input, partials);
    sph_mix<<<(BB * COUT * KK) / 256, 256, 0, stream>>>(partials, coeff, out);
}